// Round 5
// baseline (452.419 us; speedup 1.0000x reference)
//
#include <hip/hip_runtime.h>
#include <hip/hip_bf16.h>

#define IN_F  128
#define HID_F 256
#define OUT_F 64

typedef __attribute__((ext_vector_type(8))) short bf16x8;
typedef __attribute__((ext_vector_type(4))) float f32x4;

__device__ __forceinline__ float bf2f(unsigned short u) {
    union { unsigned int i; float f; } v; v.i = ((unsigned int)u) << 16; return v.f;
}
__device__ __forceinline__ float bf2f_lo(unsigned int p) {
    union { unsigned int i; float f; } v; v.i = p << 16; return v.f;
}
__device__ __forceinline__ float bf2f_hi(unsigned int p) {
    union { unsigned int i; float f; } v; v.i = p & 0xffff0000u; return v.f;
}
__device__ __forceinline__ unsigned short f2bf(float f) {
    __hip_bfloat16 b = __float2bfloat16(f);
    return *reinterpret_cast<unsigned short*>(&b);
}

// ---- x fp32 -> bf16 (8 elems/thread) ------------------------------------
__global__ __launch_bounds__(256) void k_xconv(
    const float* __restrict__ x, unsigned short* __restrict__ xb, long long total8)
{
    long long i = (long long)blockIdx.x * blockDim.x + threadIdx.x;
    if (i >= total8) return;
    const float4* p = reinterpret_cast<const float4*>(x) + i * 2;
    float4 a = p[0], b = p[1];
    ushort4 o0, o1;
    o0.x = f2bf(a.x); o0.y = f2bf(a.y); o0.z = f2bf(a.z); o0.w = f2bf(a.w);
    o1.x = f2bf(b.x); o1.y = f2bf(b.y); o1.z = f2bf(b.z); o1.w = f2bf(b.w);
    reinterpret_cast<ushort4*>(xb)[i * 2]     = o0;
    reinterpret_cast<ushort4*>(xb)[i * 2 + 1] = o1;
}

// ---- Direct CSR build: global-atomic degree -> scan -> atomic place -----
// Replaces the 6-kernel bucketed multisplit. Global atomics on a 400KB
// L2-resident counter array are cheap (G12); intra-row edge order is
// arbitrary, which is fine for sum aggregation.

__global__ __launch_bounds__(256) void k_deg(
    const int* __restrict__ dst, int* __restrict__ deg, int nEdges)
{
    int i4 = blockIdx.x * blockDim.x + threadIdx.x;
    int stride = gridDim.x * blockDim.x;
    int n4 = nEdges >> 2;
    for (int i = i4; i < n4; i += stride) {
        int4 d = reinterpret_cast<const int4*>(dst)[i];
        atomicAdd(&deg[d.x], 1); atomicAdd(&deg[d.y], 1);
        atomicAdd(&deg[d.z], 1); atomicAdd(&deg[d.w], 1);
    }
    for (int e = (n4 << 2) + i4; e < nEdges; e += stride)
        atomicAdd(&deg[dst[e]], 1);
}

// scanA: each block scans 1024 degrees -> local-exclusive rowptr + partial
__global__ __launch_bounds__(256) void k_scanA(
    const int* __restrict__ deg, int* __restrict__ rowptr,
    int* __restrict__ partial, int nNodes)
{
    __shared__ int sh[256];
    int t = threadIdx.x;
    int base = blockIdx.x * 1024 + t * 4;
    int d0 = 0, d1 = 0, d2 = 0, d3 = 0;
    if (base + 3 < nNodes) {
        int4 v = *reinterpret_cast<const int4*>(deg + base);
        d0 = v.x; d1 = v.y; d2 = v.z; d3 = v.w;
    } else {
        if (base + 0 < nNodes) d0 = deg[base + 0];
        if (base + 1 < nNodes) d1 = deg[base + 1];
        if (base + 2 < nNodes) d2 = deg[base + 2];
        if (base + 3 < nNodes) d3 = deg[base + 3];
    }
    int s = d0 + d1 + d2 + d3;
    sh[t] = s; __syncthreads();
    for (int d = 1; d < 256; d <<= 1) {
        int add = (t >= d) ? sh[t - d] : 0;
        __syncthreads();
        sh[t] += add;
        __syncthreads();
    }
    int excl = sh[t] - s;
    if (t == 255) partial[blockIdx.x] = sh[255];
    if (base + 0 < nNodes) rowptr[base + 0] = excl;
    if (base + 1 < nNodes) rowptr[base + 1] = excl + d0;
    if (base + 2 < nNodes) rowptr[base + 2] = excl + d0 + d1;
    if (base + 3 < nNodes) rowptr[base + 3] = excl + d0 + d1 + d2;
}

// scanB: one block exclusive-scans the block partials (nb <= 256)
__global__ __launch_bounds__(256) void k_scanB(int* __restrict__ partial, int nb)
{
    __shared__ int sh[256];
    int t = threadIdx.x;
    int v = (t < nb) ? partial[t] : 0;
    sh[t] = v; __syncthreads();
    for (int d = 1; d < 256; d <<= 1) {
        int add = (t >= d) ? sh[t - d] : 0;
        __syncthreads();
        sh[t] += add;
        __syncthreads();
    }
    if (t < nb) partial[t] = sh[t] - v;
}

// scanC: add block offsets; materialize cursor copy; finalize rowptr[n]
__global__ __launch_bounds__(256) void k_scanC(
    int* __restrict__ rowptr, int* __restrict__ cursor,
    const int* __restrict__ partial, int nNodes, int nEdges)
{
    int i = blockIdx.x * 1024 + threadIdx.x * 4;
    int off = partial[blockIdx.x];
    #pragma unroll
    for (int j = 0; j < 4; ++j) {
        if (i + j < nNodes) {
            int r = rowptr[i + j] + off;
            rowptr[i + j] = r;
            cursor[i + j] = r;
        }
    }
    if (blockIdx.x == 0 && threadIdx.x == 0) rowptr[nNodes] = nEdges;
}

// place: scatter src into eidx at atomically-claimed row positions
__global__ __launch_bounds__(256) void k_place(
    const int* __restrict__ src, const int* __restrict__ dst,
    int* __restrict__ cursor, int* __restrict__ eidx, int nEdges)
{
    int i4 = blockIdx.x * blockDim.x + threadIdx.x;
    int stride = gridDim.x * blockDim.x;
    int n4 = nEdges >> 2;
    for (int i = i4; i < n4; i += stride) {
        int4 s = reinterpret_cast<const int4*>(src)[i];
        int4 d = reinterpret_cast<const int4*>(dst)[i];
        int p0 = atomicAdd(&cursor[d.x], 1); eidx[p0] = s.x;
        int p1 = atomicAdd(&cursor[d.y], 1); eidx[p1] = s.y;
        int p2 = atomicAdd(&cursor[d.z], 1); eidx[p2] = s.z;
        int p3 = atomicAdd(&cursor[d.w], 1); eidx[p3] = s.w;
    }
    for (int e = (n4 << 2) + i4; e < nEdges; e += stride) {
        int p = atomicAdd(&cursor[dst[e]], 1); eidx[p] = src[e];
    }
}

// ---- Weight swizzle: fp32 W -> bf16 in B-fragment order -----------------
__global__ __launch_bounds__(256) void k_wconv(
    const float* __restrict__ W1, const float* __restrict__ W2,
    unsigned short* __restrict__ w1s, unsigned short* __restrict__ w2s)
{
    int idx = blockIdx.x * blockDim.x + threadIdx.x;
    if (idx < IN_F * HID_F) {            // W1: 16 ntiles x 4 ksteps
        int c = idx >> 9, L = (idx >> 3) & 63, j = idx & 7;
        int ntile = c >> 2, kstep = c & 3;
        int k = kstep * 32 + (L >> 4) * 8 + j;
        int n = ntile * 16 + (L & 15);
        w1s[idx] = f2bf(W1[k * HID_F + n]);
    }
    if (idx < HID_F * OUT_F) {           // W2: 4 ntiles x 8 ksteps
        int c = idx >> 9, L = (idx >> 3) & 63, j = idx & 7;
        int ntile = c >> 3, kstep = c & 7;
        int k = kstep * 32 + (L >> 4) * 8 + j;
        int n = ntile * 16 + (L & 15);
        w2s[idx] = f2bf(W2[k * OUT_F + n]);
    }
}

// ---- Layer-1 gather: agg[n] = xb[n] + sum xb[src] -----------------------
// Wide-gather: one wave = one node; 16 lanes cover a 256B row (dwordx4 per
// lane), so one instruction gathers 4 edges' rows.
__global__ __launch_bounds__(256) void gather1(
    const unsigned short* __restrict__ xb, const int* __restrict__ rowptr,
    const int* __restrict__ eidx, unsigned short* __restrict__ agg, int nNodes)
{
    int n    = blockIdx.x * 4 + __builtin_amdgcn_readfirstlane(threadIdx.x >> 6);
    int lane = threadIdx.x & 63;
    if (n >= nNodes) return;
    int beg = __builtin_amdgcn_readfirstlane(rowptr[n]);
    int end = __builtin_amdgcn_readfirstlane(rowptr[n + 1]);
    int g = lane >> 4;          // edge subgroup 0..3
    int f = lane & 15;          // 16B chunk within row
    float acc[8] = {0.f, 0.f, 0.f, 0.f, 0.f, 0.f, 0.f, 0.f};

    for (int e0 = beg; e0 < end; e0 += 64) {
        int cnt = min(64, end - e0);                 // uniform
        int e = (lane < cnt) ? eidx[e0 + lane] : 0;
        for (int i = 0; i < cnt; i += 16) {          // 16 edges per block
            uint4 v[4];
            unsigned int vmask[4];
            #pragma unroll
            for (int j = 0; j < 4; ++j) {
                int eij = i + 4 * j + g;
                int src = __builtin_amdgcn_ds_bpermute(eij << 2, e);
                int s0  = __builtin_amdgcn_readlane(e, i + 4 * j);
                bool valid = eij < cnt;
                vmask[j] = valid ? 0xffffffffu : 0u;
                src = valid ? src : s0;              // same lines, no extra fetch
                v[j] = *reinterpret_cast<const uint4*>(
                    xb + (unsigned)src * IN_F + (f << 3));
            }
            #pragma unroll
            for (int j = 0; j < 4; ++j) {
                unsigned int a0 = v[j].x & vmask[j], a1 = v[j].y & vmask[j];
                unsigned int a2 = v[j].z & vmask[j], a3 = v[j].w & vmask[j];
                acc[0] += bf2f_lo(a0); acc[1] += bf2f_hi(a0);
                acc[2] += bf2f_lo(a1); acc[3] += bf2f_hi(a1);
                acc[4] += bf2f_lo(a2); acc[5] += bf2f_hi(a2);
                acc[6] += bf2f_lo(a3); acc[7] += bf2f_hi(a3);
            }
        }
    }
    // cross-subgroup reduce (lanes f, f+16, f+32, f+48 hold same features)
    #pragma unroll
    for (int k = 0; k < 8; ++k) {
        acc[k] += __shfl_xor(acc[k], 16);
        acc[k] += __shfl_xor(acc[k], 32);
    }
    // self row add (all lanes redundantly; values identical across groups)
    uint4 sv = *reinterpret_cast<const uint4*>(xb + (size_t)n * IN_F + (f << 3));
    acc[0] += bf2f_lo(sv.x); acc[1] += bf2f_hi(sv.x);
    acc[2] += bf2f_lo(sv.y); acc[3] += bf2f_hi(sv.y);
    acc[4] += bf2f_lo(sv.z); acc[5] += bf2f_hi(sv.z);
    acc[6] += bf2f_lo(sv.w); acc[7] += bf2f_hi(sv.w);
    if (g == 0) {
        uint4 o;
        o.x = (unsigned int)f2bf(acc[0]) | ((unsigned int)f2bf(acc[1]) << 16);
        o.y = (unsigned int)f2bf(acc[2]) | ((unsigned int)f2bf(acc[3]) << 16);
        o.z = (unsigned int)f2bf(acc[4]) | ((unsigned int)f2bf(acc[5]) << 16);
        o.w = (unsigned int)f2bf(acc[6]) | ((unsigned int)f2bf(acc[7]) << 16);
        *reinterpret_cast<uint4*>(agg + (size_t)n * IN_F + (f << 3)) = o;
    }
}

// ---- Fused MLP (MFMA): z[M,64] = (agg[M,128] @ W1) @ W2, bf16 out -------
__global__ __launch_bounds__(256) void mlp_fused(
    const unsigned short* __restrict__ agg,
    const unsigned short* __restrict__ w1s,
    const unsigned short* __restrict__ w2s,
    unsigned short* __restrict__ z, int nNodes)
{
    __shared__ unsigned short h1t[4 * 16 * HID_F];   // 4 waves x 8 KB
    int wave = threadIdx.x >> 6, lane = threadIdx.x & 63;
    int m0 = blockIdx.x * 64 + wave * 16;
    if (m0 >= nNodes) return;
    int row = lane & 15, quad = lane >> 4;
    unsigned short* myt = h1t + wave * 16 * HID_F;

    // ---- gemm1: acc1 = agg_tile @ W1 ----
    f32x4 acc1[16] = {};
    const bf16x8* aBase = reinterpret_cast<const bf16x8*>(
        agg + (size_t)(m0 + row) * IN_F + quad * 8);
    const bf16x8* b1Base = reinterpret_cast<const bf16x8*>(w1s) + lane;
    #pragma unroll
    for (int ks = 0; ks < 4; ++ks) {
        bf16x8 a = aBase[ks * 4];
        #pragma unroll
        for (int nt = 0; nt < 16; ++nt) {
            bf16x8 b = b1Base[(nt * 4 + ks) * 64];
            acc1[nt] = __builtin_amdgcn_mfma_f32_16x16x32_bf16(a, b, acc1[nt], 0, 0, 0);
        }
    }

    // ---- spill h1 tile to LDS (bf16, XOR-swizzled rows) ----
    #pragma unroll
    for (int i = 0; i < 4; ++i) {
        int r = quad * 4 + i;
        #pragma unroll
        for (int nt = 0; nt < 16; ++nt) {
            int c = nt * 16 + row;
            int b = ((r << 9) + (c << 1)) ^ ((r & 7) << 4);
            myt[b >> 1] = f2bf(acc1[nt][i]);
        }
    }
    // same-wave RAW on LDS: compiler inserts lgkmcnt wait; no barrier needed

    // ---- gemm2: acc2 = h1_tile @ W2 ----
    f32x4 acc2[4] = {};
    const bf16x8* b2Base = reinterpret_cast<const bf16x8*>(w2s) + lane;
    #pragma unroll
    for (int ks = 0; ks < 8; ++ks) {
        int b = ((row << 9) + ((quad * 8 + ks * 32) << 1)) ^ ((row & 7) << 4);
        bf16x8 a = *reinterpret_cast<const bf16x8*>(&myt[b >> 1]);
        #pragma unroll
        for (int nt = 0; nt < 4; ++nt) {
            bf16x8 bb = b2Base[(nt * 8 + ks) * 64];
            acc2[nt] = __builtin_amdgcn_mfma_f32_16x16x32_bf16(a, bb, acc2[nt], 0, 0, 0);
        }
    }
    size_t outBase = (size_t)(m0 + quad * 4) * OUT_F + row;
    #pragma unroll
    for (int i = 0; i < 4; ++i) {
        if (m0 + quad * 4 + i >= nNodes) break;   // tail guard
        #pragma unroll
        for (int nt = 0; nt < 4; ++nt)
            z[outBase + (size_t)i * OUT_F + nt * 16] = f2bf(acc2[nt][i]);
    }
}

// ---- Layer-2 gather (commuted): out[n] = z[n] + sum z[src] --------------
// Wide-gather: 8 lanes cover a 128B z-row (dwordx4/lane) -> 8 edges/instr.
__global__ __launch_bounds__(256) void gather2(
    const unsigned short* __restrict__ z, const int* __restrict__ rowptr,
    const int* __restrict__ eidx, float* __restrict__ out, int nNodes)
{
    int n    = blockIdx.x * 4 + __builtin_amdgcn_readfirstlane(threadIdx.x >> 6);
    int lane = threadIdx.x & 63;
    if (n >= nNodes) return;
    int beg = __builtin_amdgcn_readfirstlane(rowptr[n]);
    int end = __builtin_amdgcn_readfirstlane(rowptr[n + 1]);
    int g = lane >> 3;          // edge subgroup 0..7
    int f = lane & 7;           // 16B chunk within row
    float acc[8] = {0.f, 0.f, 0.f, 0.f, 0.f, 0.f, 0.f, 0.f};

    for (int e0 = beg; e0 < end; e0 += 64) {
        int cnt = min(64, end - e0);                 // uniform
        int e = (lane < cnt) ? eidx[e0 + lane] : 0;
        for (int i = 0; i < cnt; i += 32) {          // 32 edges per block
            uint4 v[4];
            unsigned int vmask[4];
            #pragma unroll
            for (int j = 0; j < 4; ++j) {
                int eij = i + 8 * j + g;
                int src = __builtin_amdgcn_ds_bpermute(eij << 2, e);
                int s0  = __builtin_amdgcn_readlane(e, i + 8 * j);
                bool valid = eij < cnt;
                vmask[j] = valid ? 0xffffffffu : 0u;
                src = valid ? src : s0;
                v[j] = *reinterpret_cast<const uint4*>(
                    z + (unsigned)src * OUT_F + (f << 3));
            }
            #pragma unroll
            for (int j = 0; j < 4; ++j) {
                unsigned int a0 = v[j].x & vmask[j], a1 = v[j].y & vmask[j];
                unsigned int a2 = v[j].z & vmask[j], a3 = v[j].w & vmask[j];
                acc[0] += bf2f_lo(a0); acc[1] += bf2f_hi(a0);
                acc[2] += bf2f_lo(a1); acc[3] += bf2f_hi(a1);
                acc[4] += bf2f_lo(a2); acc[5] += bf2f_hi(a2);
                acc[6] += bf2f_lo(a3); acc[7] += bf2f_hi(a3);
            }
        }
    }
    // cross-subgroup reduce (8 groups share feature chunks)
    #pragma unroll
    for (int k = 0; k < 8; ++k) {
        acc[k] += __shfl_xor(acc[k], 8);
        acc[k] += __shfl_xor(acc[k], 16);
        acc[k] += __shfl_xor(acc[k], 32);
    }
    // self row add
    uint4 sv = *reinterpret_cast<const uint4*>(z + (size_t)n * OUT_F + (f << 3));
    acc[0] += bf2f_lo(sv.x); acc[1] += bf2f_hi(sv.x);
    acc[2] += bf2f_lo(sv.y); acc[3] += bf2f_hi(sv.y);
    acc[4] += bf2f_lo(sv.z); acc[5] += bf2f_hi(sv.z);
    acc[6] += bf2f_lo(sv.w); acc[7] += bf2f_hi(sv.w);
    if (g == 0) {
        float* o = out + (size_t)n * OUT_F + (f << 3);
        *reinterpret_cast<float4*>(o)     = make_float4(acc[0], acc[1], acc[2], acc[3]);
        *reinterpret_cast<float4*>(o + 4) = make_float4(acc[4], acc[5], acc[6], acc[7]);
    }
}

extern "C" void kernel_launch(void* const* d_in, const int* in_sizes, int n_in,
                              void* d_out, int out_size, void* d_ws, size_t ws_size,
                              hipStream_t stream) {
    const float* x  = (const float*)d_in[0];
    const int* esrc = (const int*)d_in[1];
    const int* edst = (const int*)d_in[2];
    const float* W1 = (const float*)d_in[3];
    const float* W2 = (const float*)d_in[4];
    float* out      = (float*)d_out;

    const int nNodes = in_sizes[0] / IN_F;
    const int nEdges = in_sizes[1];

    // Workspace (~72 MB; 110.4 MB known-safe), 64B-aligned segments.
    char* ws = (char*)d_ws;
    size_t off = 0;
    auto alloc = [&](size_t bytes) {
        char* p = ws + off; off = (off + bytes + 63) & ~(size_t)63; return p;
    };
    unsigned short* xb  = (unsigned short*)alloc((size_t)nNodes * IN_F * 2);
    unsigned short* agg = (unsigned short*)alloc((size_t)nNodes * IN_F * 2);
    unsigned short* z   = (unsigned short*)alloc((size_t)nNodes * OUT_F * 2);
    int* eidx           = (int*)alloc((size_t)nEdges * 4);
    unsigned short* w1s = (unsigned short*)alloc((size_t)IN_F * HID_F * 2);
    unsigned short* w2s = (unsigned short*)alloc((size_t)HID_F * OUT_F * 2);
    int* rowptr         = (int*)alloc((size_t)(nNodes + 1) * 4);
    int* cursor         = (int*)alloc((size_t)nNodes * 4);
    int* deg            = (int*)alloc((size_t)nNodes * 4);
    int* partial        = (int*)alloc(256 * 4);

    k_wconv<<<(IN_F * HID_F + 255) / 256, 256, 0, stream>>>(W1, W2, w1s, w2s);

    long long total8 = (long long)nNodes * IN_F / 8;
    k_xconv<<<(int)((total8 + 255) / 256), 256, 0, stream>>>(x, xb, total8);

    // ---- CSR build ----
    hipMemsetAsync(deg, 0, (size_t)nNodes * 4, stream);
    const int n4 = nEdges >> 2;
    const int eBlocks = (n4 + 255) / 256;                  // 1563
    const int sBlocks = (nNodes + 1023) / 1024;            // 98 (<=256)
    k_deg<<<eBlocks, 256, 0, stream>>>(edst, deg, nEdges);
    k_scanA<<<sBlocks, 256, 0, stream>>>(deg, rowptr, partial, nNodes);
    k_scanB<<<1, 256, 0, stream>>>(partial, sBlocks);
    k_scanC<<<sBlocks, 256, 0, stream>>>(rowptr, cursor, partial, nNodes, nEdges);
    k_place<<<eBlocks, 256, 0, stream>>>(esrc, edst, cursor, eidx, nEdges);

    const int nBlocks = (nNodes + 3) / 4;
    const int mBlocks = (nNodes + 63) / 64;
    gather1<<<nBlocks, 256, 0, stream>>>(xb, rowptr, eidx, agg, nNodes);
    mlp_fused<<<mBlocks, 256, 0, stream>>>(agg, w1s, w2s, z, nNodes);
    gather2<<<nBlocks, 256, 0, stream>>>(z, rowptr, eidx, out, nNodes);
}

// Round 6
// 306.443 us; speedup vs baseline: 1.4764x; 1.4764x over previous
//
#include <hip/hip_runtime.h>
#include <hip/hip_bf16.h>

#define IN_F  128
#define HID_F 256
#define OUT_F 64
#define BUCKET_SHIFT 9
#define BUCKET_SZ 512
#define EPB 8192            // edges per binning block

typedef __attribute__((ext_vector_type(8))) short bf16x8;
typedef __attribute__((ext_vector_type(4))) float f32x4;

__device__ __forceinline__ float bf2f(unsigned short u) {
    union { unsigned int i; float f; } v; v.i = ((unsigned int)u) << 16; return v.f;
}
__device__ __forceinline__ float bf2f_lo(unsigned int p) {
    union { unsigned int i; float f; } v; v.i = p << 16; return v.f;
}
__device__ __forceinline__ float bf2f_hi(unsigned int p) {
    union { unsigned int i; float f; } v; v.i = p & 0xffff0000u; return v.f;
}
__device__ __forceinline__ unsigned short f2bf(float f) {
    __hip_bfloat16 b = __float2bfloat16(f);
    return *reinterpret_cast<unsigned short*>(&b);
}

// ---- Fused front: xconv | wconv | hist (independent, one launch) --------
// bid < xBlocks            : x fp32 -> bf16 (8 elems/thread)
// xBlocks <= bid < +128    : weight swizzle
// else                     : per-block LDS histogram over buckets
__global__ __launch_bounds__(256) void k_front(
    const float* __restrict__ x, unsigned short* __restrict__ xb, long long total8,
    const float* __restrict__ W1, const float* __restrict__ W2,
    unsigned short* __restrict__ w1s, unsigned short* __restrict__ w2s,
    const int* __restrict__ edst, int* __restrict__ counts, int nEdges, int A,
    int xBlocks)
{
    __shared__ int hist[256];
    int bid = blockIdx.x;
    int t = threadIdx.x;
    if (bid < xBlocks) {
        long long i = (long long)bid * 256 + t;
        if (i >= total8) return;
        const float4* p = reinterpret_cast<const float4*>(x) + i * 2;
        float4 a = p[0], b = p[1];
        ushort4 o0, o1;
        o0.x = f2bf(a.x); o0.y = f2bf(a.y); o0.z = f2bf(a.z); o0.w = f2bf(a.w);
        o1.x = f2bf(b.x); o1.y = f2bf(b.y); o1.z = f2bf(b.z); o1.w = f2bf(b.w);
        reinterpret_cast<ushort4*>(xb)[i * 2]     = o0;
        reinterpret_cast<ushort4*>(xb)[i * 2 + 1] = o1;
    } else if (bid < xBlocks + 128) {
        int idx = (bid - xBlocks) * 256 + t;
        if (idx < IN_F * HID_F) {            // W1: 16 ntiles x 4 ksteps
            int c = idx >> 9, L = (idx >> 3) & 63, j = idx & 7;
            int ntile = c >> 2, kstep = c & 3;
            int k = kstep * 32 + (L >> 4) * 8 + j;
            int n = ntile * 16 + (L & 15);
            w1s[idx] = f2bf(W1[k * HID_F + n]);
        }
        if (idx < HID_F * OUT_F) {           // W2: 4 ntiles x 8 ksteps
            int c = idx >> 9, L = (idx >> 3) & 63, j = idx & 7;
            int ntile = c >> 3, kstep = c & 7;
            int k = kstep * 32 + (L >> 4) * 8 + j;
            int n = ntile * 16 + (L & 15);
            w2s[idx] = f2bf(W2[k * OUT_F + n]);
        }
    } else {
        int hb = bid - xBlocks - 128;        // histogram block 0..A-1
        hist[t] = 0;
        __syncthreads();
        long long base = (long long)hb * EPB;
        #pragma unroll
        for (int k = 0; k < EPB / 256; ++k) {
            long long e = base + k * 256 + t;
            if (e < nEdges) atomicAdd(&hist[edst[e] >> BUCKET_SHIFT], 1);
        }
        __syncthreads();
        // NB <= 256 buckets
        counts[t * A + hb] = hist[t];
    }
}

// Phase 2a: bucket totals (NB blocks, parallel reduce over A counts each).
__global__ __launch_bounds__(256) void k_btot(
    const int* __restrict__ counts, int* __restrict__ btot, int A)
{
    __shared__ int sh[256];
    int b = blockIdx.x, t = threadIdx.x;
    int s = 0;
    for (int i = t; i < A; i += 256) s += counts[(size_t)b * A + i];
    sh[t] = s; __syncthreads();
    for (int d = 128; d > 0; d >>= 1) {
        if (t < d) sh[t] += sh[t + d];
        __syncthreads();
    }
    if (t == 0) btot[b] = sh[0];
}

// Phase 2b: one block scans NB totals -> bucketBase (exclusive).
__global__ __launch_bounds__(256) void k_scanNB(
    const int* __restrict__ btot, int* __restrict__ bucketBase,
    int* __restrict__ rowptr, int NB, int nNodes, int nEdges)
{
    __shared__ int sh[256];
    int t = threadIdx.x;
    int v = (t < NB) ? btot[t] : 0;
    sh[t] = v; __syncthreads();
    for (int d = 1; d < 256; d <<= 1) {
        int add = (t >= d) ? sh[t - d] : 0;
        __syncthreads();
        sh[t] += add;
        __syncthreads();
    }
    if (t < NB) bucketBase[t] = sh[t] - v;
    if (t == 0) { bucketBase[NB] = nEdges; rowptr[nNodes] = nEdges; }
}

// Phase 2c: per-bucket exclusive scan of its A counts + base -> start cursors.
__global__ __launch_bounds__(256) void k_cursor(
    int* __restrict__ counts, const int* __restrict__ bucketBase, int A)
{
    __shared__ int sh[256];
    int b = blockIdx.x, t = threadIdx.x;
    int run = bucketBase[b];
    for (int base = 0; base < A; base += 256) {
        int idx = base + t;
        int v = (idx < A) ? counts[(size_t)b * A + idx] : 0;
        sh[t] = v; __syncthreads();
        for (int d = 1; d < 256; d <<= 1) {
            int add = (t >= d) ? sh[t - d] : 0;
            __syncthreads();
            sh[t] += add;
            __syncthreads();
        }
        if (idx < A) counts[(size_t)b * A + idx] = run + sh[t] - v;
        run += sh[255];
        __syncthreads();
    }
}

// Phase 3: place packed (dlocal,src) into bucket-contiguous binned[] (4B).
// dlocal needs 9 bits, src < 2^23: pack = (dlocal<<23) | src.
__global__ __launch_bounds__(256) void k_bin(
    const int* __restrict__ src, const int* __restrict__ dst,
    const int* __restrict__ counts, unsigned int* __restrict__ binned,
    int nEdges, int A)
{
    __shared__ int cur[256];
    int t = threadIdx.x;
    cur[t] = counts[t * A + blockIdx.x];
    __syncthreads();
    long long base = (long long)blockIdx.x * EPB;
    #pragma unroll
    for (int k = 0; k < EPB / 256; ++k) {
        long long e = base + k * 256 + t;
        if (e < nEdges) {
            int s = src[e], d = dst[e];
            int pos = atomicAdd(&cur[d >> BUCKET_SHIFT], 1);
            binned[pos] = (((unsigned int)(d & (BUCKET_SZ - 1))) << 23) | (unsigned int)s;
        }
    }
}

// Phase 4: per-bucket local CSR: LDS deg hist -> LDS scan -> rowptr + eidx.
__global__ __launch_bounds__(256) void k_localcsr(
    const unsigned int* __restrict__ binned, const int* __restrict__ bucketBase,
    int* __restrict__ rowptr, int* __restrict__ eidx, int nNodes)
{
    __shared__ int ldeg[BUCKET_SZ];
    __shared__ int lscan[256];
    int t = threadIdx.x;
    ldeg[t] = 0; ldeg[t + 256] = 0;
    __syncthreads();
    int eb0 = bucketBase[blockIdx.x], eb1 = bucketBase[blockIdx.x + 1];
    int node0 = blockIdx.x << BUCKET_SHIFT;
    for (int e = eb0 + t; e < eb1; e += 256) {
        int dl = (int)(binned[e] >> 23);
        atomicAdd(&ldeg[dl], 1);
    }
    __syncthreads();
    int d0 = ldeg[2 * t], d1 = ldeg[2 * t + 1];
    int s = d0 + d1;
    lscan[t] = s;
    __syncthreads();
    for (int d = 1; d < 256; d <<= 1) {
        int add = (t >= d) ? lscan[t - d] : 0;
        __syncthreads();
        lscan[t] += add;
        __syncthreads();
    }
    int excl = lscan[t] - s;
    ldeg[2 * t]     = excl;        // becomes local cursor
    ldeg[2 * t + 1] = excl + d0;
    int n0 = node0 + 2 * t;
    if (n0 < nNodes)     rowptr[n0]     = eb0 + excl;
    if (n0 + 1 < nNodes) rowptr[n0 + 1] = eb0 + excl + d0;
    __syncthreads();
    for (int e = eb0 + t; e < eb1; e += 256) {
        unsigned int p = binned[e];
        int dl = (int)(p >> 23), sv = (int)(p & 0x7fffffu);
        int pos = atomicAdd(&ldeg[dl], 1);
        eidx[eb0 + pos] = sv;
    }
}

// ---- Layer-1 gather: agg[n] = xb[n] + sum xb[src] -----------------------
// Wide-gather: one wave = one node; 16 lanes cover a 256B row (dwordx4 per
// lane), so one instruction gathers 4 edges' rows.
__global__ __launch_bounds__(256) void gather1(
    const unsigned short* __restrict__ xb, const int* __restrict__ rowptr,
    const int* __restrict__ eidx, unsigned short* __restrict__ agg, int nNodes)
{
    int n    = blockIdx.x * 4 + __builtin_amdgcn_readfirstlane(threadIdx.x >> 6);
    int lane = threadIdx.x & 63;
    if (n >= nNodes) return;
    int beg = __builtin_amdgcn_readfirstlane(rowptr[n]);
    int end = __builtin_amdgcn_readfirstlane(rowptr[n + 1]);
    int g = lane >> 4;          // edge subgroup 0..3
    int f = lane & 15;          // 16B chunk within row
    float acc[8] = {0.f, 0.f, 0.f, 0.f, 0.f, 0.f, 0.f, 0.f};

    for (int e0 = beg; e0 < end; e0 += 64) {
        int cnt = min(64, end - e0);                 // uniform
        int e = (lane < cnt) ? eidx[e0 + lane] : 0;
        for (int i = 0; i < cnt; i += 16) {          // 16 edges per block
            uint4 v[4];
            unsigned int vmask[4];
            #pragma unroll
            for (int j = 0; j < 4; ++j) {
                int eij = i + 4 * j + g;
                int src = __builtin_amdgcn_ds_bpermute(eij << 2, e);
                int s0  = __builtin_amdgcn_readlane(e, i + 4 * j);
                bool valid = eij < cnt;
                vmask[j] = valid ? 0xffffffffu : 0u;
                src = valid ? src : s0;              // same lines, no extra fetch
                v[j] = *reinterpret_cast<const uint4*>(
                    xb + (unsigned)src * IN_F + (f << 3));
            }
            #pragma unroll
            for (int j = 0; j < 4; ++j) {
                unsigned int a0 = v[j].x & vmask[j], a1 = v[j].y & vmask[j];
                unsigned int a2 = v[j].z & vmask[j], a3 = v[j].w & vmask[j];
                acc[0] += bf2f_lo(a0); acc[1] += bf2f_hi(a0);
                acc[2] += bf2f_lo(a1); acc[3] += bf2f_hi(a1);
                acc[4] += bf2f_lo(a2); acc[5] += bf2f_hi(a2);
                acc[6] += bf2f_lo(a3); acc[7] += bf2f_hi(a3);
            }
        }
    }
    // cross-subgroup reduce (lanes f, f+16, f+32, f+48 hold same features)
    #pragma unroll
    for (int k = 0; k < 8; ++k) {
        acc[k] += __shfl_xor(acc[k], 16);
        acc[k] += __shfl_xor(acc[k], 32);
    }
    // self row add (all lanes redundantly; values identical across groups)
    uint4 sv = *reinterpret_cast<const uint4*>(xb + (size_t)n * IN_F + (f << 3));
    acc[0] += bf2f_lo(sv.x); acc[1] += bf2f_hi(sv.x);
    acc[2] += bf2f_lo(sv.y); acc[3] += bf2f_hi(sv.y);
    acc[4] += bf2f_lo(sv.z); acc[5] += bf2f_hi(sv.z);
    acc[6] += bf2f_lo(sv.w); acc[7] += bf2f_hi(sv.w);
    if (g == 0) {
        uint4 o;
        o.x = (unsigned int)f2bf(acc[0]) | ((unsigned int)f2bf(acc[1]) << 16);
        o.y = (unsigned int)f2bf(acc[2]) | ((unsigned int)f2bf(acc[3]) << 16);
        o.z = (unsigned int)f2bf(acc[4]) | ((unsigned int)f2bf(acc[5]) << 16);
        o.w = (unsigned int)f2bf(acc[6]) | ((unsigned int)f2bf(acc[7]) << 16);
        *reinterpret_cast<uint4*>(agg + (size_t)n * IN_F + (f << 3)) = o;
    }
}

// ---- Fused MLP (MFMA): z[M,64] = (agg[M,128] @ W1) @ W2, bf16 out -------
__global__ __launch_bounds__(256) void mlp_fused(
    const unsigned short* __restrict__ agg,
    const unsigned short* __restrict__ w1s,
    const unsigned short* __restrict__ w2s,
    unsigned short* __restrict__ z, int nNodes)
{
    __shared__ unsigned short h1t[4 * 16 * HID_F];   // 4 waves x 8 KB
    int wave = threadIdx.x >> 6, lane = threadIdx.x & 63;
    int m0 = blockIdx.x * 64 + wave * 16;
    if (m0 >= nNodes) return;
    int row = lane & 15, quad = lane >> 4;
    unsigned short* myt = h1t + wave * 16 * HID_F;

    // ---- gemm1: acc1 = agg_tile @ W1 ----
    f32x4 acc1[16] = {};
    const bf16x8* aBase = reinterpret_cast<const bf16x8*>(
        agg + (size_t)(m0 + row) * IN_F + quad * 8);
    const bf16x8* b1Base = reinterpret_cast<const bf16x8*>(w1s) + lane;
    #pragma unroll
    for (int ks = 0; ks < 4; ++ks) {
        bf16x8 a = aBase[ks * 4];
        #pragma unroll
        for (int nt = 0; nt < 16; ++nt) {
            bf16x8 b = b1Base[(nt * 4 + ks) * 64];
            acc1[nt] = __builtin_amdgcn_mfma_f32_16x16x32_bf16(a, b, acc1[nt], 0, 0, 0);
        }
    }

    // ---- spill h1 tile to LDS (bf16, XOR-swizzled rows) ----
    #pragma unroll
    for (int i = 0; i < 4; ++i) {
        int r = quad * 4 + i;
        #pragma unroll
        for (int nt = 0; nt < 16; ++nt) {
            int c = nt * 16 + row;
            int b = ((r << 9) + (c << 1)) ^ ((r & 7) << 4);
            myt[b >> 1] = f2bf(acc1[nt][i]);
        }
    }
    // same-wave RAW on LDS: compiler inserts lgkmcnt wait; no barrier needed

    // ---- gemm2: acc2 = h1_tile @ W2 ----
    f32x4 acc2[4] = {};
    const bf16x8* b2Base = reinterpret_cast<const bf16x8*>(w2s) + lane;
    #pragma unroll
    for (int ks = 0; ks < 8; ++ks) {
        int b = ((row << 9) + ((quad * 8 + ks * 32) << 1)) ^ ((row & 7) << 4);
        bf16x8 a = *reinterpret_cast<const bf16x8*>(&myt[b >> 1]);
        #pragma unroll
        for (int nt = 0; nt < 4; ++nt) {
            bf16x8 bb = b2Base[(nt * 8 + ks) * 64];
            acc2[nt] = __builtin_amdgcn_mfma_f32_16x16x32_bf16(a, bb, acc2[nt], 0, 0, 0);
        }
    }
    size_t outBase = (size_t)(m0 + quad * 4) * OUT_F + row;
    #pragma unroll
    for (int i = 0; i < 4; ++i) {
        if (m0 + quad * 4 + i >= nNodes) break;   // tail guard
        #pragma unroll
        for (int nt = 0; nt < 4; ++nt)
            z[outBase + (size_t)i * OUT_F + nt * 16] = f2bf(acc2[nt][i]);
    }
}

// ---- Layer-2 gather (commuted): out[n] = z[n] + sum z[src] --------------
// Wide-gather: 8 lanes cover a 128B z-row (dwordx4/lane) -> 8 edges/instr.
__global__ __launch_bounds__(256) void gather2(
    const unsigned short* __restrict__ z, const int* __restrict__ rowptr,
    const int* __restrict__ eidx, float* __restrict__ out, int nNodes)
{
    int n    = blockIdx.x * 4 + __builtin_amdgcn_readfirstlane(threadIdx.x >> 6);
    int lane = threadIdx.x & 63;
    if (n >= nNodes) return;
    int beg = __builtin_amdgcn_readfirstlane(rowptr[n]);
    int end = __builtin_amdgcn_readfirstlane(rowptr[n + 1]);
    int g = lane >> 3;          // edge subgroup 0..7
    int f = lane & 7;           // 16B chunk within row
    float acc[8] = {0.f, 0.f, 0.f, 0.f, 0.f, 0.f, 0.f, 0.f};

    for (int e0 = beg; e0 < end; e0 += 64) {
        int cnt = min(64, end - e0);                 // uniform
        int e = (lane < cnt) ? eidx[e0 + lane] : 0;
        for (int i = 0; i < cnt; i += 32) {          // 32 edges per block
            uint4 v[4];
            unsigned int vmask[4];
            #pragma unroll
            for (int j = 0; j < 4; ++j) {
                int eij = i + 8 * j + g;
                int src = __builtin_amdgcn_ds_bpermute(eij << 2, e);
                int s0  = __builtin_amdgcn_readlane(e, i + 8 * j);
                bool valid = eij < cnt;
                vmask[j] = valid ? 0xffffffffu : 0u;
                src = valid ? src : s0;
                v[j] = *reinterpret_cast<const uint4*>(
                    z + (unsigned)src * OUT_F + (f << 3));
            }
            #pragma unroll
            for (int j = 0; j < 4; ++j) {
                unsigned int a0 = v[j].x & vmask[j], a1 = v[j].y & vmask[j];
                unsigned int a2 = v[j].z & vmask[j], a3 = v[j].w & vmask[j];
                acc[0] += bf2f_lo(a0); acc[1] += bf2f_hi(a0);
                acc[2] += bf2f_lo(a1); acc[3] += bf2f_hi(a1);
                acc[4] += bf2f_lo(a2); acc[5] += bf2f_hi(a2);
                acc[6] += bf2f_lo(a3); acc[7] += bf2f_hi(a3);
            }
        }
    }
    // cross-subgroup reduce (8 groups share feature chunks)
    #pragma unroll
    for (int k = 0; k < 8; ++k) {
        acc[k] += __shfl_xor(acc[k], 8);
        acc[k] += __shfl_xor(acc[k], 16);
        acc[k] += __shfl_xor(acc[k], 32);
    }
    // self row add
    uint4 sv = *reinterpret_cast<const uint4*>(z + (size_t)n * OUT_F + (f << 3));
    acc[0] += bf2f_lo(sv.x); acc[1] += bf2f_hi(sv.x);
    acc[2] += bf2f_lo(sv.y); acc[3] += bf2f_hi(sv.y);
    acc[4] += bf2f_lo(sv.z); acc[5] += bf2f_hi(sv.z);
    acc[6] += bf2f_lo(sv.w); acc[7] += bf2f_hi(sv.w);
    if (g == 0) {
        float* o = out + (size_t)n * OUT_F + (f << 3);
        *reinterpret_cast<float4*>(o)     = make_float4(acc[0], acc[1], acc[2], acc[3]);
        *reinterpret_cast<float4*>(o + 4) = make_float4(acc[4], acc[5], acc[6], acc[7]);
    }
}

extern "C" void kernel_launch(void* const* d_in, const int* in_sizes, int n_in,
                              void* d_out, int out_size, void* d_ws, size_t ws_size,
                              hipStream_t stream) {
    const float* x  = (const float*)d_in[0];
    const int* esrc = (const int*)d_in[1];
    const int* edst = (const int*)d_in[2];
    const float* W1 = (const float*)d_in[3];
    const float* W2 = (const float*)d_in[4];
    float* out      = (float*)d_out;

    const int nNodes = in_sizes[0] / IN_F;
    const int nEdges = in_sizes[1];
    const int NB = (nNodes + BUCKET_SZ - 1) / BUCKET_SZ;   // 196 (must be <= 256)
    const int A  = (nEdges + EPB - 1) / EPB;               // 196 binning blocks

    // Workspace (~78 MB; 110.4 MB known-safe), 64B-aligned segments.
    char* ws = (char*)d_ws;
    size_t off = 0;
    auto alloc = [&](size_t bytes) {
        char* p = ws + off; off = (off + bytes + 63) & ~(size_t)63; return p;
    };
    unsigned short* xb  = (unsigned short*)alloc((size_t)nNodes * IN_F * 2);
    unsigned short* agg = (unsigned short*)alloc((size_t)nNodes * IN_F * 2);
    unsigned short* z   = (unsigned short*)alloc((size_t)nNodes * OUT_F * 2);
    unsigned int* binned = (unsigned int*)alloc((size_t)nEdges * 4);
    int* eidx           = (int*)alloc((size_t)nEdges * 4);
    unsigned short* w1s = (unsigned short*)alloc((size_t)IN_F * HID_F * 2);
    unsigned short* w2s = (unsigned short*)alloc((size_t)HID_F * OUT_F * 2);
    int* rowptr         = (int*)alloc((size_t)(nNodes + 1) * 4);
    int* counts         = (int*)alloc((size_t)NB * A * 4);
    int* bucketBase     = (int*)alloc((size_t)(NB + 1) * 4);
    int* btot           = (int*)alloc((size_t)NB * 4);

    // ---- fused front: xconv | wconv | hist ----
    long long total8 = (long long)nNodes * IN_F / 8;
    const int xBlocks = (int)((total8 + 255) / 256);       // 6250
    k_front<<<xBlocks + 128 + A, 256, 0, stream>>>(
        x, xb, total8, W1, W2, w1s, w2s, edst, counts, nEdges, A, xBlocks);

    // ---- CSR build (bucketed multisplit, 4B packed records) ----
    k_btot<<<NB, 256, 0, stream>>>(counts, btot, A);
    k_scanNB<<<1, 256, 0, stream>>>(btot, bucketBase, rowptr, NB, nNodes, nEdges);
    k_cursor<<<NB, 256, 0, stream>>>(counts, bucketBase, A);
    k_bin<<<A, 256, 0, stream>>>(esrc, edst, counts, binned, nEdges, A);
    k_localcsr<<<NB, 256, 0, stream>>>(binned, bucketBase, rowptr, eidx, nNodes);

    const int nBlocks = (nNodes + 3) / 4;
    const int mBlocks = (nNodes + 63) / 64;
    gather1<<<nBlocks, 256, 0, stream>>>(xb, rowptr, eidx, agg, nNodes);
    mlp_fused<<<mBlocks, 256, 0, stream>>>(agg, w1s, w2s, z, nNodes);
    gather2<<<nBlocks, 256, 0, stream>>>(z, rowptr, eidx, out, nNodes);
}